// Round 11
// baseline (279.485 us; speedup 1.0000x reference)
//
#include <hip/hip_runtime.h>
#include <math.h>

#define HDIM 4096
#define NEXP 64
#define NTOK 8192
#define KSPLIT 4
#define KSLICE (HDIM / KSPLIT)   // 1024
#define BM 64                    // token rows per block (16 per wave)
#define CHUNK 32
#define SECT 256                 // floats per A-section (1 KB per row)
#define NSECT (KSLICE / SECT)    // 4
#define CPS (SECT / CHUNK)       // 8 chunks per section
#define PSTRIDE 2048             // shorts: one (chunk,part) plane = 64 experts * 32 k
#define CSTRIDE 6144             // shorts: 3 parts per chunk
#define AUXCOPIES 32
#define AUXF (AUXCOPIES * 128)   // floats of auxbuf
#define BSF 393216               // floats holding 786432 shorts of pre-split B
#define SLICEOFF (AUXF + BSF)    // slices start here (floats)
#define TPW 2
#define TOPK_BLOCKS (NTOK / (4 * TPW))  // 1024

typedef short short8 __attribute__((ext_vector_type(8)));
typedef float f32x4 __attribute__((ext_vector_type(4)));

// Exact 3-way bf16 split of two fp32 values, packed as (lo16=x0, hi16=x1).
__device__ __forceinline__ void split2x3(float x0, float x1, int& h, int& md, int& lo) {
  unsigned u0 = __float_as_uint(x0), u1 = __float_as_uint(x1);
  unsigned h0 = u0 & 0xFFFF0000u, h1 = u1 & 0xFFFF0000u;
  float r0 = x0 - __uint_as_float(h0);
  float r1 = x1 - __uint_as_float(h1);
  unsigned m0 = __float_as_uint(r0) & 0xFFFF0000u;
  unsigned m1 = __float_as_uint(r1) & 0xFFFF0000u;
  float s0 = r0 - __uint_as_float(m0);
  float s1 = r1 - __uint_as_float(m1);
  h  = (int)((h0 >> 16) | h1);
  md = (int)((m0 >> 16) | m1);
  lo = (int)((__float_as_uint(s0) >> 16) | (__float_as_uint(s1) & 0xFFFF0000u));
}

__device__ __forceinline__ short8 pack_s8(int a, int b, int c, int d) {
  union { int i[4]; short8 s; } u;
  u.i[0] = a; u.i[1] = b; u.i[2] = c; u.i[3] = d;
  return u.s;
}

// ---------------------------------------------------------------------------
// Pre-split gate_w into bf16x3 planes [chunk c][part][expert][32 k] (round-2
// verified layout). 1.5 MB, L2-resident. gemm reads fragments from it with
// FULLY CONTIGUOUS 1KB wave-loads (lane off = l15*32+quad*8 shorts = 16B/lane
// in lane order). Block 0 also zeroes auxbuf.
// ---------------------------------------------------------------------------
__global__ void bsplit_k(const float* __restrict__ W, short* __restrict__ Bs,
                         float* __restrict__ wsbase) {
  const int e = blockIdx.x;      // 64 experts
  const int tid = threadIdx.x;   // 256
  if (e == 0) {
#pragma unroll
    for (int t = tid; t < AUXF; t += 256) wsbase[t] = 0.f;
  }
#pragma unroll
  for (int it = 0; it < 2; ++it) {
    const int k0 = tid * 16 + it * 8;  // 0..4088
    const float4 v0 = *(const float4*)&W[(size_t)e * HDIM + k0];
    const float4 v1 = *(const float4*)&W[(size_t)e * HDIM + k0 + 4];
    const float f[8] = {v0.x, v0.y, v0.z, v0.w, v1.x, v1.y, v1.z, v1.w};
    int h[4], md[4], lo[4];
#pragma unroll
    for (int j = 0; j < 4; ++j) split2x3(f[2 * j], f[2 * j + 1], h[j], md[j], lo[j]);
    const int c = k0 >> 5, kk = k0 & 31;
    short* p = Bs + (size_t)c * CSTRIDE + (size_t)e * 32 + kk;
    *(int4*)(p)               = make_int4(h[0], h[1], h[2], h[3]);
    *(int4*)(p + PSTRIDE)     = make_int4(md[0], md[1], md[2], md[3]);
    *(int4*)(p + 2 * PSTRIDE) = make_int4(lo[0], lo[1], lo[2], lo[3]);
  }
}

// ---------------------------------------------------------------------------
// GEMM v8: CONTIGUOUS-LOAD redesign.
// Round-10 diagnosis: three structurally different schedules (LDS+barrier,
// barrier-free LDS, no-LDS) all ~90µs with every pipe <25% busy. The
// INVARIANT was the address pattern: every load instruction's 64 lanes
// touched 16 rows at 16KB stride = 16 scattered cache-line groups/instr;
// the per-CU address path serializes scattered segments (~4-9cy/line), so
// line-request throughput was the wall, untouched by scheduling.
// v8 makes every global load a single contiguous 1KB run:
//  - A: wave owns 16 full rows. Per section (256 floats), 16 loads, each =
//    ONE row's 1KB section (lane l -> +l*16B). Redistribute via wave-private
//    LDS [16][256] (write contiguous, read fragments ds_read_b128).
//    No barriers: waves touch only their own LDS rows.
//  - W: pre-split planes (bsplit_k) -> 12 contiguous 1KB fragment loads per
//    chunk, L2-hot, zero in-loop W VALU.
// vmcnt ledger per chunk: W(12) issued, [c==7: A(s+1)(16) issued after],
// then vmcnt(0) (c<7) / vmcnt(16) (c==7, drains W, leaves A in flight across
// the section boundary; in-order retirement). A-split (bf16x3) at fragment
// time — identical arithmetic to all passing rounds.
// ---------------------------------------------------------------------------
__global__ __launch_bounds__(256, 2) void gemm_k(const float* __restrict__ A,
                                                 const short* __restrict__ Bs,
                                                 float* __restrict__ Lp,
                                                 int atomic_mode) {
  __shared__ __align__(16) float As[BM * SECT];  // 64 KB, wave-private quarters
  const int tid = threadIdx.x;
  const int m_base = blockIdx.x * BM;
  const int k_base = blockIdx.y * KSLICE;
  float* Lout = Lp + (atomic_mode ? (size_t)0 : (size_t)blockIdx.y * NTOK * NEXP);

  const int lane = tid & 63;
  const int wave = tid >> 6;
  const int l15 = lane & 15;
  const int quad = lane >> 4;

  // A: contiguous staging. Row j of this wave = m_base + wave*16 + j.
  const float* aBase = A + (size_t)(m_base + wave * 16) * HDIM + k_base + lane * 4;
  float* wlds = &As[(wave * 16) * SECT];                       // write side
  const float* rlds = &As[(wave * 16 + l15) * SECT + quad * 8]; // fragment side

  // W: fragment plane base (contiguous 1KB per (nt,part) instr)
  const short* bBase = Bs + (size_t)(k_base >> 5) * CSTRIDE + l15 * 32 + quad * 8;

  f32x4 acc[4];
#pragma unroll
  for (int nt = 0; nt < 4; ++nt) acc[nt] = (f32x4){0.f, 0.f, 0.f, 0.f};

  float4 st[16];  // staging regs; static indices only (rule #20)
  // prologue: A(section 0)
#pragma unroll
  for (int j = 0; j < 16; ++j)
    st[j] = *(const float4*)(aBase + (size_t)j * HDIM);

  for (int s = 0; s < NSECT; ++s) {
    // A(s) arrival: only vmem outstanding at section top
    asm volatile("s_waitcnt vmcnt(0)" ::: "memory");
    __builtin_amdgcn_sched_barrier(0);
#pragma unroll
    for (int j = 0; j < 16; ++j)
      *(float4*)&wlds[j * SECT + lane * 4] = st[j];  // contiguous, 2-way free

#pragma unroll
    for (int c = 0; c < CPS; ++c) {
      // W(c): 12 contiguous 1KB loads (oldest vmem this chunk)
      const short* bp = bBase + (size_t)(s * CPS + c) * CSTRIDE;
      short8 bw[12];
#pragma unroll
      for (int nt = 0; nt < 4; ++nt)
#pragma unroll
        for (int p = 0; p < 3; ++p)
          bw[nt * 3 + p] = *(const short8*)(bp + nt * 512 + p * PSTRIDE);
      __builtin_amdgcn_sched_barrier(0);  // pin: W issue before A(s+1) issue

      if (c == CPS - 1 && s + 1 < NSECT) {
#pragma unroll
        for (int j = 0; j < 16; ++j)
          st[j] = *(const float4*)(aBase + (size_t)j * HDIM + (s + 1) * SECT);
      }
      __builtin_amdgcn_sched_barrier(0);  // pin: all loads above compute

      // A fragment from own-wave LDS rows + bf16x3 split (covers W L2 latency)
      const float4 a0 = *(const float4*)&rlds[c * 32];
      const float4 a1 = *(const float4*)&rlds[c * 32 + 4];
      const float f[8] = {a0.x, a0.y, a0.z, a0.w, a1.x, a1.y, a1.z, a1.w};
      int h[4], md[4], lo[4];
#pragma unroll
      for (int j = 0; j < 4; ++j) split2x3(f[2 * j], f[2 * j + 1], h[j], md[j], lo[j]);
      const short8 fh = pack_s8(h[0], h[1], h[2], h[3]);
      const short8 fm = pack_s8(md[0], md[1], md[2], md[3]);
      const short8 fl = pack_s8(lo[0], lo[1], lo[2], lo[3]);

      // drain W(c); on the section's last chunk keep A(s+1) in flight
      if (c == CPS - 1 && s + 1 < NSECT)
        asm volatile("s_waitcnt vmcnt(16)" ::: "memory");
      else
        asm volatile("s_waitcnt vmcnt(0)" ::: "memory");
      __builtin_amdgcn_sched_barrier(0);

#pragma unroll
      for (int nt = 0; nt < 4; ++nt) {
        const short8 bh = bw[nt * 3 + 0];
        const short8 bmid = bw[nt * 3 + 1];
        const short8 blo = bw[nt * 3 + 2];
        f32x4 cacc = acc[nt];
        cacc = __builtin_amdgcn_mfma_f32_16x16x32_bf16(fh, bh, cacc, 0, 0, 0);
        cacc = __builtin_amdgcn_mfma_f32_16x16x32_bf16(fh, bmid, cacc, 0, 0, 0);
        cacc = __builtin_amdgcn_mfma_f32_16x16x32_bf16(fm, bh, cacc, 0, 0, 0);
        cacc = __builtin_amdgcn_mfma_f32_16x16x32_bf16(fh, blo, cacc, 0, 0, 0);
        cacc = __builtin_amdgcn_mfma_f32_16x16x32_bf16(fl, bh, cacc, 0, 0, 0);
        cacc = __builtin_amdgcn_mfma_f32_16x16x32_bf16(fm, bmid, cacc, 0, 0, 0);
        acc[nt] = cacc;
      }
    }
  }

#pragma unroll
  for (int nt = 0; nt < 4; ++nt)
#pragma unroll
    for (int r = 0; r < 4; ++r) {
      const int m = m_base + wave * 16 + quad * 4 + r;
      const int n = nt * 16 + l15;
      if (atomic_mode) atomicAdd(&Lout[(size_t)m * NEXP + n], acc[nt][r]);
      else Lout[(size_t)m * NEXP + n] = acc[nt][r];
    }
}

// ---------------------------------------------------------------------------
// Top-k router v3 (round-5 verified; KSPLIT macro now 4): wave-per-token-pair,
// reg-prefetched slice loads, interleaved reduce chains, single barrier.
// ---------------------------------------------------------------------------
__global__ __launch_bounds__(256) void topk_k(const float* __restrict__ Lp, int nsl,
                                              float* __restrict__ out,
                                              float* __restrict__ auxbuf) {
  __shared__ float sl[2][4][64];
  __shared__ float s_aux[128];  // [0:64) prob sums, [64:128) pick counts
  const int tid = threadIdx.x;
  const int wave = tid >> 6, lane = tid & 63;
  if (tid < 128) s_aux[tid] = 0.f;

  const int t0 = (blockIdx.x * 4 + wave) * TPW;
  float x0 = 0.f, x1 = 0.f;
  if (nsl == KSPLIT) {
    float v[2][KSPLIT];
#pragma unroll
    for (int tok = 0; tok < 2; ++tok)
#pragma unroll
      for (int s = 0; s < KSPLIT; ++s)
        v[tok][s] = Lp[(size_t)s * (NTOK * NEXP) + (size_t)(t0 + tok) * NEXP + lane];
#pragma unroll
    for (int s = 0; s < KSPLIT; ++s) { x0 += v[0][s]; x1 += v[1][s]; }
  } else {
    for (int s = 0; s < nsl; ++s) {
      x0 += Lp[(size_t)s * (NTOK * NEXP) + (size_t)t0 * NEXP + lane];
      x1 += Lp[(size_t)s * (NTOK * NEXP) + (size_t)(t0 + 1) * NEXP + lane];
    }
  }
  sl[0][wave][lane] = x0;
  sl[1][wave][lane] = x1;

  float m0 = x0, m1 = x1;
#pragma unroll
  for (int off = 32; off >= 1; off >>= 1) {
    m0 = fmaxf(m0, __shfl_xor(m0, off, 64));
    m1 = fmaxf(m1, __shfl_xor(m1, off, 64));
  }
  const float e0 = __expf(x0 - m0), e1 = __expf(x1 - m1);
  float ss0 = e0, ss1 = e1;
#pragma unroll
  for (int off = 32; off >= 1; off >>= 1) {
    ss0 += __shfl_xor(ss0, off, 64);
    ss1 += __shfl_xor(ss1, off, 64);
  }
  const float p0 = e0 / ss0, p1 = e1 / ss1;

  __syncthreads();  // sl + s_aux-init visible

  int c0 = 0, c1 = 0;
#pragma unroll
  for (int c = 0; c < 4; ++c) {
#pragma unroll
    for (int tok = 0; tok < 2; ++tok) {
      const float4 w0 = *(const float4*)&sl[tok][wave][c * 16 + 0];
      const float4 w1 = *(const float4*)&sl[tok][wave][c * 16 + 4];
      const float4 w2 = *(const float4*)&sl[tok][wave][c * 16 + 8];
      const float4 w3 = *(const float4*)&sl[tok][wave][c * 16 + 12];
      const float xv[16] = {w0.x, w0.y, w0.z, w0.w, w1.x, w1.y, w1.z, w1.w,
                            w2.x, w2.y, w2.z, w2.w, w3.x, w3.y, w3.z, w3.w};
      const float xr = tok ? x1 : x0;
      int cc = 0;
#pragma unroll
      for (int j = 0; j < 16; ++j) {
        const int jj = c * 16 + j;
        cc += (xv[j] > xr) || (xv[j] == xr && jj < lane);
      }
      if (tok) c1 += cc; else c0 += cc;
    }
  }

  float tp0 = (c0 < 8) ? p0 : 0.f;
  float tp1 = (c1 < 8) ? p1 : 0.f;
  float ts0 = tp0, ts1 = tp1;
#pragma unroll
  for (int off = 32; off >= 1; off >>= 1) {
    ts0 += __shfl_xor(ts0, off, 64);
    ts1 += __shfl_xor(ts1, off, 64);
  }

  const float pv0 = __uint_as_float(
      (unsigned)__builtin_amdgcn_ds_permute(c0 << 2, (int)__float_as_uint(p0)));
  const int pi0 = __builtin_amdgcn_ds_permute(c0 << 2, lane);
  const float pv1 = __uint_as_float(
      (unsigned)__builtin_amdgcn_ds_permute(c1 << 2, (int)__float_as_uint(p1)));
  const int pi1 = __builtin_amdgcn_ds_permute(c1 << 2, lane);
  if (lane < 8) {
    out[(size_t)t0 * 8 + lane] = pv0 / ts0;
    out[(size_t)NTOK * 8 + (size_t)t0 * 8 + lane] = (float)pi0;
    out[(size_t)(t0 + 1) * 8 + lane] = pv1 / ts1;
    out[(size_t)NTOK * 8 + (size_t)(t0 + 1) * 8 + lane] = (float)pi1;
  }
  atomicAdd(&s_aux[lane], p0 + p1);
  const float cadd = (c0 < 8 ? 1.f : 0.f) + (c1 < 8 ? 1.f : 0.f);
  atomicAdd(&s_aux[64 + lane], cadd);

  __syncthreads();
  if (tid < 128)
    atomicAdd(&auxbuf[(blockIdx.x & (AUXCOPIES - 1)) * 128 + tid], s_aux[tid]);
}

// aux = E * sum_e (count_e/(T*K)) * (sumprob_e/T), over AUXCOPIES copies
__global__ void aux_k(const float* __restrict__ auxbuf, float* __restrict__ out) {
  const int e = threadIdx.x;  // 64 threads
  float p = 0.f, f = 0.f;
#pragma unroll
  for (int c = 0; c < AUXCOPIES; ++c) {
    p += auxbuf[c * 128 + e];
    f += auxbuf[c * 128 + 64 + e];
  }
  p *= (1.f / (float)NTOK);
  f *= (1.f / ((float)NTOK * 8.f));
  float v = f * p;
#pragma unroll
  for (int off = 32; off >= 1; off >>= 1) v += __shfl_xor(v, off, 64);
  if (e == 0) out[2 * NTOK * 8] = 64.f * v;
}

extern "C" void kernel_launch(void* const* d_in, const int* in_sizes, int n_in,
                              void* d_out, int out_size, void* d_ws, size_t ws_size,
                              hipStream_t stream) {
  const float* hidden = (const float*)d_in[0];  // 8192 x 4096 fp32
  const float* gate = (const float*)d_in[1];    // 64 x 4096 fp32
  float* out = (float*)d_out;                   // [w 65536 | idx 65536 | aux 1]
  float* ws = (float*)d_ws;
  float* auxbuf = ws;                           // AUXCOPIES x 128 floats
  short* Bs = (short*)(ws + AUXF);              // pre-split B, 1.5 MB
  float* slices = ws + SLICEOFF;                // KSPLIT x (8192*64) fp32 partials

  const size_t need = (size_t)SLICEOFF * 4 + (size_t)KSPLIT * NTOK * NEXP * 4;
  const int atomic_mode = (ws_size < need) ? 1 : 0;
  const int nsl = atomic_mode ? 1 : KSPLIT;

  if (atomic_mode)  // fallback only; zeroes aux region + logits accumulator
    hipMemsetAsync(d_ws, 0, (size_t)SLICEOFF * 4 + (size_t)NTOK * NEXP * 4, stream);

  bsplit_k<<<NEXP, 256, 0, stream>>>(gate, Bs, ws);  // also zeroes auxbuf
  gemm_k<<<dim3(NTOK / BM, KSPLIT), 256, 0, stream>>>(hidden, Bs, slices,
                                                      atomic_mode);
  topk_k<<<TOPK_BLOCKS, 256, 0, stream>>>(slices, nsl, out, auxbuf);
  aux_k<<<1, 64, 0, stream>>>(auxbuf, out);
}